// Round 5
// baseline (1582.327 us; speedup 1.0000x reference)
//
#include <hip/hip_runtime.h>
#include <cmath>

// Problem dims (fixed by the reference)
constexpr int kB = 32, kH = 48, kT = 24, kS = 256, kA = 64, kR = 8, kF = 1024;
constexpr int kSEQ = kH + 1;           // 49 = history + present step
constexpr float kEPS = 1e-5f;

// Persistent-kernel config: 128 blocks x 512 thr (8 waves).
// Blocks 0..63: layer-0 f-tiles (16 cols). Blocks 64..127: layer-1.
// Blocks 0..31 also run the fused head stage (one batch each).
constexpr int G  = 128;
constexpr int BT = 512;

typedef __attribute__((ext_vector_type(8))) short short8;   // 8 x bf16
typedef __attribute__((ext_vector_type(4))) float f32x4;

union U4S8 { uint4 u; short8 s; };

__device__ __forceinline__ unsigned bfbits(float x) {  // RNE f32->bf16
  unsigned u = __float_as_uint(x);
  return (u + 0x7fffu + ((u >> 16) & 1u)) >> 16;
}
__device__ __forceinline__ float bf_lo(unsigned u) { return __uint_as_float(u << 16); }
__device__ __forceinline__ float bf_hi(unsigned u) { return __uint_as_float(u & 0xffff0000u); }
__device__ __forceinline__ float bf2f(unsigned short h) {
  return __uint_as_float(((unsigned)h) << 16);
}
__device__ __forceinline__ float gelu_f(float x) {
  return 0.5f * x * (1.0f + erff(x * 0.7071067811865476f));
}
__device__ __forceinline__ float sigmoid_f(float x) {
  return 1.0f / (1.0f + expf(-x));
}

// sc1 (LLC write-through) store: makes produced data visible to all XCDs.
__device__ __forceinline__ void coh_st(unsigned* p, unsigned v) {
  __hip_atomic_store(p, v, __ATOMIC_RELAXED, __HIP_MEMORY_SCOPE_AGENT);
}

// ---------------- R13: producer-count flag sync ----------------------------
// Each flag = 4 lines x 128B. Producer group g bumps line (g&3): 16 adders
// per line (R10-proven contention level). Consumers poll all 4 lines in ONE
// vmcnt round trip. One LLC hop total (vs the tree's 3 serial hops), and
// each wait involves only the true producer set -- idle sets never gate.
// Protocol: producer calls sig() only after a __syncthreads() that follows
// its stores (compiler drains vmcnt before s_barrier -> stores at LLC).
__device__ __forceinline__ void sig(unsigned* fl, int grp) {
  if (threadIdx.x == 0)
    __hip_atomic_fetch_add(fl + (grp & 3) * 32, 1u,
                           __ATOMIC_RELAXED, __HIP_MEMORY_SCOPE_AGENT);
}
__device__ __forceinline__ void wait4(const unsigned* fl,
                                      unsigned t0, unsigned t1,
                                      unsigned t2, unsigned t3) {
  if (threadIdx.x == 0) {
    for (;;) {
      unsigned a, b, c, d;
      asm volatile(
        "global_load_dword %0, %4, off sc0 sc1\n\t"
        "global_load_dword %1, %5, off sc0 sc1\n\t"
        "global_load_dword %2, %6, off sc0 sc1\n\t"
        "global_load_dword %3, %7, off sc0 sc1\n\t"
        "s_waitcnt vmcnt(0)"
        : "=&v"(a), "=&v"(b), "=&v"(c), "=&v"(d)
        : "v"(fl), "v"(fl + 32), "v"(fl + 64), "v"(fl + 96)
        : "memory");
      if (a >= t0 && b >= t1 && c >= t2 && d >= t3) break;
    }
  }
  __syncthreads();
}

// ---------------- one GRU layer step via MFMA (R10-identical) --------------
// Block owns 16 f-cols of one layer. Wave wv = k-slice [wv*128, wv*128+128).
// B-frags (weights) resident in VGPRs. Sets: 0=r(i+h), 1=z(i+h), 2=n_i, 3=n_h.
// x/h inputs are PLAIN CACHED loads: every stage reads a buffer address never
// touched before in this launch (rotation) -> L2 must miss and fill from LLC.
__device__ __forceinline__ void layer_stage(
    const unsigned short* __restrict__ xsrc,   // [32][1024] bf16
    const unsigned short* __restrict__ hsrc,   // [32][1024] bf16
    unsigned short* __restrict__ hdst,         // [32][1024] bf16 (sc1 stores)
    const short8 (&Bf)[2][3][4],
    float bR, float bZ, float bIN, float bHN,
    float& h_old, float* part, int fb)
{
  const int tid = threadIdx.x;
  const int wv = tid >> 6, l = tid & 63, q = l >> 4, c = l & 15;

  short8 Afr[2][2][4];
  #pragma unroll
  for (int mt = 0; mt < 2; mt++)
    #pragma unroll
    for (int j = 0; j < 4; j++) {
      const int off = (mt*16 + c)*1024 + wv*128 + j*32 + q*8;
      Afr[0][mt][j] = *(const short8*)(xsrc + off);
      Afr[1][mt][j] = *(const short8*)(hsrc + off);
    }

  f32x4 C[4][2];
  #pragma unroll
  for (int s = 0; s < 4; s++)
    #pragma unroll
    for (int mt = 0; mt < 2; mt++)
      C[s][mt] = (f32x4){0.f, 0.f, 0.f, 0.f};

  #pragma unroll
  for (int mt = 0; mt < 2; mt++)
    #pragma unroll
    for (int j = 0; j < 4; j++) {
      C[0][mt] = __builtin_amdgcn_mfma_f32_16x16x32_bf16(Afr[0][mt][j], Bf[0][0][j], C[0][mt], 0, 0, 0);
      C[0][mt] = __builtin_amdgcn_mfma_f32_16x16x32_bf16(Afr[1][mt][j], Bf[1][0][j], C[0][mt], 0, 0, 0);
      C[1][mt] = __builtin_amdgcn_mfma_f32_16x16x32_bf16(Afr[0][mt][j], Bf[0][1][j], C[1][mt], 0, 0, 0);
      C[1][mt] = __builtin_amdgcn_mfma_f32_16x16x32_bf16(Afr[1][mt][j], Bf[1][1][j], C[1][mt], 0, 0, 0);
      C[2][mt] = __builtin_amdgcn_mfma_f32_16x16x32_bf16(Afr[0][mt][j], Bf[0][2][j], C[2][mt], 0, 0, 0);
      C[3][mt] = __builtin_amdgcn_mfma_f32_16x16x32_bf16(Afr[1][mt][j], Bf[1][2][j], C[3][mt], 0, 0, 0);
    }

  // k-slice partials -> LDS (swizzled: 2-way/bank over 64 lanes = free).
  const int perm = (wv + l + (l >> 3)) & 7;
  #pragma unroll
  for (int s = 0; s < 4; s++)
    #pragma unroll
    for (int mt = 0; mt < 2; mt++)
      #pragma unroll
      for (int r = 0; r < 4; r++)
        part[((s*2 + mt)*4 + r)*512 + l*8 + perm] = C[s][mt][r];
  __syncthreads();

  // combine: wave wv -> (mtile = wv&1, reg = wv>>1); lane -> one (b,f)
  const int mt_c = wv & 1, rg = wv >> 1;
  const int b_own = mt_c*16 + q*4 + rg;
  float S[4];
  #pragma unroll
  for (int s = 0; s < 4; s++) {
    const float* pp = part + ((s*2 + mt_c)*4 + rg)*512 + l*8;
    f32x4 a = *(const f32x4*)pp;
    f32x4 b = *(const f32x4*)(pp + 4);
    S[s] = ((a[0]+a[1]) + (a[2]+a[3])) + ((b[0]+b[1]) + (b[2]+b[3]));
  }
  float rr = sigmoid_f(S[0] + bR);
  float zz = sigmoid_f(S[1] + bZ);
  float nn = tanhf(S[2] + bIN + rr * (S[3] + bHN));
  float hn = (1.f - zz)*nn + zz*h_old;
  h_old = hn;
  float nb = __shfl_xor(hn, 1);
  if (!(c & 1)) {
    unsigned pk = bfbits(hn) | (bfbits(nb) << 16);
    coh_st((unsigned*)(hdst + b_own*1024 + fb*16 + c), pk);
  }
  __syncthreads();   // drains stores (compiler waitcnt) -> safe to sig() after
}

// ---------------- fused head + LN + pres + gelu (blocks 0..31, b=blk) ------
// Weight loads coalesced via transposed layouts (R12).
//   WsT2[(k>>1)*512 + j*2 + (k&1)] = W_sout[j][k]   (dword = k-pair for col j)
//   WstT[k*1024 + f]               = W_state[f][k]  (dword = (f0,f0+1) at k)
__device__ __forceinline__ void f3_stage(
    const unsigned short* __restrict__ y_bf, int t,
    const unsigned short* __restrict__ WsT2_bf, const float* __restrict__ b_sout,
    const unsigned short* __restrict__ Wr_bf, const float* __restrict__ b_reward,
    const unsigned short* __restrict__ WstT_bf, const float* __restrict__ b_state,
    const float* __restrict__ g_sn, const float* __restrict__ b_sn,
    const unsigned short* __restrict__ fa_bf,
    float* __restrict__ out_r, float* __restrict__ out_s,
    unsigned short* __restrict__ xbuf_bf, float* part, int b)
{
  const int tid = threadIdx.x;
  float* yb    = part;          // 1024: y in f32
  float* spart = part + 1024;   // 512
  float* s_sh  = part + 1536;   // 256
  float* rpart = part + 1792;   // 64
  float* red1  = part + 2048;   // 512
  float* red2  = part + 2560;   // 512

  {
    unsigned uu = *((const unsigned*)y_bf + b*512 + tid);   // cached (fresh buf)
    yb[tid*2]     = bf_lo(uu);
    yb[tid*2 + 1] = bf_hi(uu);
  }
  __syncthreads();
  {  // s partials: j = tid&255, k-half = tid>>8; coalesced dword loads
    const int j = tid & 255, ksh = tid >> 8;
    const unsigned* wp = (const unsigned*)WsT2_bf + (size_t)ksh*256*256 + j;
    const float* yp = yb + ksh*512;
    float acc = 0.f;
    #pragma unroll 8
    for (int kp = 0; kp < 256; kp++) {
      unsigned w = wp[kp*256];
      acc += bf_lo(w)*yp[2*kp] + bf_hi(w)*yp[2*kp + 1];
    }
    spart[tid] = acc;
  }
  __syncthreads();
  if (tid < 256) {
    float s = spart[tid] + spart[tid + 256] + b_sout[tid];
    out_s[((size_t)b*kT + t)*kS + tid] = s;
    s_sh[tid] = s;
  } else if (tid < 320) {
    const int idx = tid - 256, j = idx >> 3, ks = idx & 7;
    const unsigned short* wr = Wr_bf + j*1024 + ks*128;
    const float* yp = yb + ks*128;
    float acc = 0.f;
    #pragma unroll 4
    for (int k = 0; k < 128; k += 2) {
      unsigned w = *(const unsigned*)(wr + k);
      acc += bf_lo(w)*yp[k] + bf_hi(w)*yp[k+1];
    }
    rpart[idx] = acc;
  }
  __syncthreads();
  if (tid < 8) {
    float a = b_reward[tid];
    #pragma unroll
    for (int ks = 0; ks < 8; ks++) a += rpart[tid*8 + ks];
    out_r[((size_t)b*kT + t)*kR + tid] = tanhf(a);
  }
  if (t == kT - 1) return;   // uniform branch: last step needs no next-x
  __syncthreads();
  // u[f] = b_state[f] + W_state[f,:] @ s ; LN over 1024; x = gelu(LN + fa[t+1])
  const int f0 = tid*2;
  float a0 = b_state[f0], a1 = b_state[f0 + 1];
  {
    const unsigned* wp = (const unsigned*)WstT_bf + (f0 >> 1);
    #pragma unroll 8
    for (int k = 0; k < 256; k++) {
      unsigned w = wp[k*512];
      a0 += bf_lo(w)*s_sh[k];
      a1 += bf_hi(w)*s_sh[k];
    }
  }
  float s1 = a0 + a1, s2 = a0*a0 + a1*a1;
  red1[tid] = s1; red2[tid] = s2;
  __syncthreads();
  for (int off = 256; off > 0; off >>= 1) {
    if (tid < off) { red1[tid] += red1[tid + off]; red2[tid] += red2[tid + off]; }
    __syncthreads();
  }
  const float mean = red1[0] * (1.0f/kF);
  const float var  = red2[0] * (1.0f/kF) - mean*mean;
  const float inv  = rsqrtf(var + kEPS);
  unsigned fu = *((const unsigned*)(fa_bf + ((size_t)(t+1)*kB + b)*kF) + tid);
  float x0 = (a0 - mean)*inv*g_sn[f0]   + b_sn[f0]   + bf_lo(fu);
  float x1 = (a1 - mean)*inv*g_sn[f0+1] + b_sn[f0+1] + bf_hi(fu);
  unsigned pk = bfbits(gelu_f(x0)) | (bfbits(gelu_f(x1)) << 16);
  coh_st((unsigned*)xbuf_bf + b*512 + tid, pk);
}

// ---------------- B-fragment preamble (shared by both kernels) -------------
__device__ __forceinline__ void load_bfrags(
    const float* __restrict__ gru_Wi, const float* __restrict__ gru_Wh,
    int lay, int fb, int wv, int q, int c, short8 (&Bf)[2][3][4])
{
  const size_t WLL = (size_t)3 * kF * kF;
  const float* Wm[2] = { gru_Wi + lay*WLL, gru_Wh + lay*WLL };
  #pragma unroll
  for (int m = 0; m < 2; m++)
    #pragma unroll
    for (int g = 0; g < 3; g++)
      #pragma unroll
      for (int j = 0; j < 4; j++) {
        const float* p = Wm[m] + ((size_t)(g*kF + fb*16 + c))*kF + wv*128 + j*32 + q*8;
        float4 a = *(const float4*)p;
        float4 b = *(const float4*)(p + 4);
        U4S8 u;
        u.u.x = bfbits(a.x) | (bfbits(a.y) << 16);
        u.u.y = bfbits(a.z) | (bfbits(a.w) << 16);
        u.u.z = bfbits(b.x) | (bfbits(b.y) << 16);
        u.u.w = bfbits(b.z) | (bfbits(b.w) << 16);
        Bf[m][g][j] = u.s;
      }
}

// ---------------- persistent kernel 1: history wavefront -------------------
// R13 flags: FH0(s) = "h0p(s) fully stored" (64 producers), FH1(s) likewise.
// L0's 49-step chain syncs only among the 64 L0 blocks; L1 trails decoupled.
__global__ __launch_bounds__(BT, 2) void gru_hist(
    const float* __restrict__ gru_Wi, const float* __restrict__ gru_Wh,
    const float* __restrict__ gru_bi, const float* __restrict__ gru_bh,
    const unsigned short* __restrict__ seq0_bf,
    unsigned short* h0pool, unsigned short* h1pool,
    unsigned* hflags)
{
  __shared__ float part[32 * 512];   // 64 KB
  const int tid = threadIdx.x;
  const int blk = blockIdx.x;
  const int wv = tid >> 6, l = tid & 63, q = l >> 4, c = l & 15;
  const bool isL1 = (blk >= 64);
  const int fb = blk & 63;
  const int grp = blk >> 4;
  const int lay = isL1 ? 1 : 0;
  const size_t BF = (size_t)kB * kF;

  short8 Bf[2][3][4];
  load_bfrags(gru_Wi, gru_Wh, lay, fb, wv, q, c, Bf);
  const int f = fb*16 + c;
  const float* bi = gru_bi + lay*3*kF;
  const float* bh = gru_bh + lay*3*kF;
  const float bR  = bi[f] + bh[f];
  const float bZ  = bi[kF + f] + bh[kF + f];
  const float bIN = bi[2*kF + f];
  const float bHN = bh[2*kF + f];

  float h_old = 0.f;

  #define H0P(i) (h0pool + (size_t)(i)*BF)
  #define H1P(i) (h1pool + (size_t)(i)*BF)
  #define FH0(s) (hflags + (size_t)((s) - 1) * 128)
  #define FH1(s) (hflags + (size_t)(49 + (s) - 1) * 128)

  // L0 at s (s<49): x=seq0[s],   h=h0p(s)   -> h0p(s+1)
  // L1 at s (s>=1): x=h0p(s),    h=h1p(s-1) -> h1p(s)
  for (int s = 0; s < 50; s++) {
    if (!isL1) {
      if (s < 49) {
        if (s >= 1) wait4(FH0(s), 16, 16, 16, 16);
        layer_stage(seq0_bf + (size_t)s*BF, H0P(s), H0P(s+1),
                    Bf, bR, bZ, bIN, bHN, h_old, part, fb);
        sig(FH0(s+1), grp);
      }
    } else {
      if (s >= 1) {
        wait4(FH0(s), 16, 16, 16, 16);
        if (s >= 2) wait4(FH1(s-1), 16, 16, 16, 16);
        layer_stage(H0P(s), H1P(s-1), H1P(s),
                    Bf, bR, bZ, bIN, bHN, h_old, part, fb);
        sig(FH1(s), grp);
      }
    }
  }
  #undef H0P
  #undef H1P
  #undef FH0
  #undef FH1
}

// ---------------- persistent kernel 2: future chain ------------------------
// R13 flags: FXF(t)=xbp(t) ready (32 producers, 2 lines); FH0F(t)=h0p(50+t);
// FH1F(t)=h1p(50+t). Waits touch only the true producer sets.
__global__ __launch_bounds__(BT, 2) void gru_fut(
    const float* __restrict__ gru_Wi, const float* __restrict__ gru_Wh,
    const float* __restrict__ gru_bi, const float* __restrict__ gru_bh,
    const unsigned short* __restrict__ WsT2_bf, const float* __restrict__ b_sout,
    const unsigned short* __restrict__ Wr_bf, const float* __restrict__ b_reward,
    const unsigned short* __restrict__ WstT_bf, const float* __restrict__ b_state,
    const float* __restrict__ g_sn, const float* __restrict__ b_sn,
    const unsigned short* __restrict__ fa_bf,
    unsigned short* h0pool, unsigned short* h1pool, unsigned short* xbpool,
    unsigned* fflags,
    float* __restrict__ out_r, float* __restrict__ out_s)
{
  __shared__ float part[32 * 512];   // 64 KB
  const int tid = threadIdx.x;
  const int blk = blockIdx.x;
  const int wv = tid >> 6, l = tid & 63, q = l >> 4, c = l & 15;
  const bool isL1 = (blk >= 64);
  const int fb = blk & 63;
  const int grp = blk >> 4;
  const int lay = isL1 ? 1 : 0;
  const size_t BF = (size_t)kB * kF;

  short8 Bf[2][3][4];
  load_bfrags(gru_Wi, gru_Wh, lay, fb, wv, q, c, Bf);
  const int f = fb*16 + c;
  const float* bi = gru_bi + lay*3*kF;
  const float* bh = gru_bh + lay*3*kF;
  const float bR  = bi[f] + bh[f];
  const float bZ  = bi[kF + f] + bh[kF + f];
  const float bIN = bi[2*kF + f];
  const float bHN = bh[2*kF + f];

  #define H0P(i) (h0pool + (size_t)(i)*BF)
  #define H1P(i) (h1pool + (size_t)(i)*BF)
  #define XBP(i) (xbpool + (size_t)(i)*BF)
  #define FXF(t)  (fflags + (size_t)(t) * 128)
  #define FH0F(t) (fflags + (size_t)(23 + (t)) * 128)
  #define FH1F(t) (fflags + (size_t)(46 + (t)) * 128)

  // h_old reload from pools (one bf16 rounding at the kernel boundary).
  const int b_own = (wv & 1)*16 + q*4 + (wv >> 1);
  float h_old;
  {
    const unsigned short* hs = isL1 ? H1P(49) : H0P(49);
    h_old = bf2f(hs[b_own*1024 + f]);
  }

  // per t: F3 -> L0 -> L1 (serial feedback chain)
  // F3 at t: y=h1p(49+t), writes xbp(t) (t<23)
  // L0 at t: x=xbp(t), h=h0p(49+t) -> h0p(50+t)
  // L1 at t: x=h0p(50+t), h=h1p(49+t) -> h1p(50+t)
  for (int t = 0; t < kT; t++) {
    if (blk < kB) {
      if (t >= 1) wait4(FH1F(t-1), 16, 16, 16, 16);
      f3_stage(H1P(49+t), t, WsT2_bf, b_sout, Wr_bf, b_reward,
               WstT_bf, b_state, g_sn, b_sn, fa_bf,
               out_r, out_s, XBP(t), part, blk);
      if (t < kT - 1) { __syncthreads(); sig(FXF(t), grp); }
    }
    if (t == kT - 1) break;
    if (!isL1) {
      wait4(FXF(t), 16, 16, 0, 0);
      if (t >= 1) wait4(FH0F(t-1), 16, 16, 16, 16);
      layer_stage(XBP(t), H0P(49+t), H0P(50+t),
                  Bf, bR, bZ, bIN, bHN, h_old, part, fb);
      sig(FH0F(t), grp);
    } else {
      wait4(FH0F(t), 16, 16, 16, 16);
      if (t >= 1) wait4(FH1F(t-1), 16, 16, 16, 16);
      layer_stage(H0P(50+t), H1P(49+t), H1P(50+t),
                  Bf, bR, bZ, bIN, bHN, h_old, part, fb);
      sig(FH1F(t), grp);
    }
  }
  #undef H0P
  #undef H1P
  #undef XBP
  #undef FXF
  #undef FH0F
  #undef FH1F
}

// ---------------- setup: convert + transpose head weights to bf16 ----------
__global__ __launch_bounds__(512) void convert_weights(
    const float* __restrict__ ws,  unsigned short* __restrict__ wsT2,
    const float* __restrict__ wst, unsigned short* __restrict__ wstT,
    const float* __restrict__ wr,  unsigned short* __restrict__ o3)
{
  const int stride = gridDim.x * blockDim.x;
  const int i0 = blockIdx.x * blockDim.x + threadIdx.x;
  // WsT2[(k>>1)*512 + j*2 + (k&1)] = bf16(W_sout[j][k]); j=i>>10, k=i&1023
  for (int i = i0; i < kS*kF; i += stride) {
    const int j = i >> 10, k = i & 1023;
    wsT2[(k >> 1)*512 + j*2 + (k & 1)] = (unsigned short)bfbits(ws[i]);
  }
  // WstT[k*1024 + f] = bf16(W_state[f][k]); f=i>>8, k=i&255
  for (int i = i0; i < kF*kS; i += stride) {
    const int ff = i >> 8, k = i & 255;
    wstT[k*1024 + ff] = (unsigned short)bfbits(wst[i]);
  }
  for (int i = i0; i < kR*kF; i += stride) o3[i] = (unsigned short)bfbits(wr[i]);
}

// ---------------- encoder: fa_bf[t][b][f] = bf16(LN(future_a@Wa^T+ba)*g+b) -
__global__ __launch_bounds__(256) void encode_fa_kernel(
    const float* __restrict__ future_a,
    const float* __restrict__ W_action, const float* __restrict__ b_action,
    const float* __restrict__ g_an, const float* __restrict__ b_an,
    unsigned short* __restrict__ fa_bf)
{
  __shared__ __align__(16) float arow[kA];
  __shared__ float red1[256], red2[256];
  const int bid = blockIdx.x;
  const int b = bid & (kB - 1);
  const int t = bid >> 5;
  const int tid = threadIdx.x;
  if (tid < kA) arow[tid] = future_a[((size_t)b*kT + t)*kA + tid];
  __syncthreads();
  float v[4]; float s1 = 0.f, s2 = 0.f;
  #pragma unroll
  for (int j = 0; j < 4; j++) {
    const int ff = tid + j*256;
    const float* wr = W_action + (size_t)ff*kA;
    float acc = b_action[ff];
    for (int k = 0; k < kA; k += 4) {
      float4 w  = *(const float4*)(wr + k);
      float4 xv = *(const float4*)(arow + k);
      acc += xv.x*w.x + xv.y*w.y + xv.z*w.z + xv.w*w.w;
    }
    v[j] = acc; s1 += acc; s2 += acc*acc;
  }
  red1[tid] = s1; red2[tid] = s2;
  __syncthreads();
  for (int off = 128; off > 0; off >>= 1) {
    if (tid < off) { red1[tid] += red1[tid+off]; red2[tid] += red2[tid+off]; }
    __syncthreads();
  }
  const float m = red1[0] * (1.0f/kF);
  const float va = red2[0] * (1.0f/kF) - m*m;
  const float inv = rsqrtf(va + kEPS);
  #pragma unroll
  for (int j = 0; j < 4; j++) {
    const int ff = tid + j*256;
    fa_bf[((size_t)t*kB + b)*kF + ff] =
        (unsigned short)bfbits((v[j] - m)*inv*g_an[ff] + b_an[ff]);
  }
}

// ---------------- encoder: seq0_bf = bf16(gelu(LN_s + LN_a)) ---------------
__global__ __launch_bounds__(256) void encode_seq0_kernel(
    const float* __restrict__ history_s, const float* __restrict__ history_a,
    const float* __restrict__ present_s,
    const float* __restrict__ W_state, const float* __restrict__ b_state,
    const float* __restrict__ g_sn, const float* __restrict__ b_sn,
    const float* __restrict__ W_action, const float* __restrict__ b_action,
    const float* __restrict__ g_an, const float* __restrict__ b_an,
    const unsigned short* __restrict__ fa_bf, unsigned short* __restrict__ seq0_bf)
{
  __shared__ __align__(16) float srow[kS];
  __shared__ __align__(16) float arow[kA];
  __shared__ float red1[256], red2[256];
  const int bid = blockIdx.x;
  const int b = bid & (kB - 1);
  const int t = bid >> 5;                 // 0..48
  const int tid = threadIdx.x;
  const bool hist = (t < kH);
  const float* sp = hist ? (history_s + ((size_t)b*kH + t)*kS)
                         : (present_s + (size_t)b*kS);
  srow[tid] = sp[tid];
  if (hist && tid < kA) arow[tid] = history_a[((size_t)b*kH + t)*kA + tid];
  __syncthreads();

  float u[4]; float s1 = 0.f, s2 = 0.f;
  #pragma unroll
  for (int j = 0; j < 4; j++) {
    const int ff = tid + j*256;
    const float* wr = W_state + (size_t)ff*kS;
    float acc = b_state[ff];
    for (int k = 0; k < kS; k += 4) {
      float4 w  = *(const float4*)(wr + k);
      float4 xv = *(const float4*)(srow + k);
      acc += xv.x*w.x + xv.y*w.y + xv.z*w.z + xv.w*w.w;
    }
    u[j] = acc; s1 += acc; s2 += acc*acc;
  }
  red1[tid] = s1; red2[tid] = s2;
  __syncthreads();
  for (int off = 128; off > 0; off >>= 1) {
    if (tid < off) { red1[tid] += red1[tid+off]; red2[tid] += red2[tid+off]; }
    __syncthreads();
  }
  const float mu = red1[0] * (1.0f/kF);
  const float vu = red2[0] * (1.0f/kF) - mu*mu;
  const float iu = rsqrtf(vu + kEPS);
  __syncthreads();

  if (hist) {
    float v[4]; s1 = 0.f; s2 = 0.f;
    #pragma unroll
    for (int j = 0; j < 4; j++) {
      const int ff = tid + j*256;
      const float* wr = W_action + (size_t)ff*kA;
      float acc = b_action[ff];
      for (int k = 0; k < kA; k += 4) {
        float4 w  = *(const float4*)(wr + k);
        float4 xv = *(const float4*)(arow + k);
        acc += xv.x*w.x + xv.y*w.y + xv.z*w.z + xv.w*w.w;
      }
      v[j] = acc; s1 += acc; s2 += acc*acc;
    }
    red1[tid] = s1; red2[tid] = s2;
    __syncthreads();
    for (int off = 128; off > 0; off >>= 1) {
      if (tid < off) { red1[tid] += red1[tid+off]; red2[tid] += red2[tid+off]; }
      __syncthreads();
    }
    const float mv = red1[0] * (1.0f/kF);
    const float vv = red2[0] * (1.0f/kF) - mv*mv;
    const float iv = rsqrtf(vv + kEPS);
    #pragma unroll
    for (int j = 0; j < 4; j++) {
      const int ff = tid + j*256;
      const float un = (u[j] - mu)*iu*g_sn[ff] + b_sn[ff];
      const float vn = (v[j] - mv)*iv*g_an[ff] + b_an[ff];
      seq0_bf[((size_t)t*kB + b)*kF + ff] = (unsigned short)bfbits(gelu_f(un + vn));
    }
  } else {
    #pragma unroll
    for (int j = 0; j < 4; j++) {
      const int ff = tid + j*256;
      const float un = (u[j] - mu)*iu*g_sn[ff] + b_sn[ff];
      seq0_bf[((size_t)t*kB + b)*kF + ff] =
          (unsigned short)bfbits(gelu_f(un + bf2f(fa_bf[(size_t)b*kF + ff])));
    }
  }
}

// ---------------- host launcher -------------------------------------------
extern "C" void kernel_launch(void* const* d_in, const int* in_sizes, int n_in,
                              void* d_out, int out_size, void* d_ws, size_t ws_size,
                              hipStream_t stream) {
  (void)in_sizes; (void)n_in; (void)out_size;
  const float* history_s = (const float*)d_in[0];
  const float* history_a = (const float*)d_in[1];
  const float* present_s = (const float*)d_in[2];
  /* d_in[3] future_s: unused by the reference forward */
  const float* future_a  = (const float*)d_in[4];
  const float* W_state   = (const float*)d_in[5];
  const float* b_state   = (const float*)d_in[6];
  const float* g_sn      = (const float*)d_in[7];
  const float* b_sn      = (const float*)d_in[8];
  const float* W_action  = (const float*)d_in[9];
  const float* b_action  = (const float*)d_in[10];
  const float* g_an      = (const float*)d_in[11];
  const float* b_an      = (const float*)d_in[12];
  const float* gru_Wi    = (const float*)d_in[13];
  const float* gru_Wh    = (const float*)d_in[14];
  const float* gru_bi    = (const float*)d_in[15];
  const float* gru_bh    = (const float*)d_in[16];
  const float* W_reward  = (const float*)d_in[17];
  const float* b_reward  = (const float*)d_in[18];
  const float* W_sout    = (const float*)d_in[19];
  const float* b_sout    = (const float*)d_in[20];

  // workspace layout (bytes, 16-aligned). Rotation pools: 73+73 h buffers
  // (64 KB each) + 23 xbuf. Flag areas: hist 98 flags, fut 69 flags, 512B ea.
  char* ws = (char*)d_ws;
  unsigned short* seq0_bf = (unsigned short*)(ws + 0);            //  3,211,264
  unsigned short* fa_bf   = (unsigned short*)(ws + 3211264);      //  1,572,864
  unsigned short* WsT2_bf = (unsigned short*)(ws + 4784128);      //    524,288
  unsigned short* WstT_bf = (unsigned short*)(ws + 5308416);      //    524,288
  unsigned short* Wr_bf   = (unsigned short*)(ws + 5832704);      //     16,384
  unsigned short* h0pool  = (unsigned short*)(ws + 5849088);      //  4,784,128 (73 x 64K)
  unsigned short* h1pool  = (unsigned short*)(ws + 10633216);     //  4,784,128 (73 x 64K)
  unsigned short* xbpool  = (unsigned short*)(ws + 15417344);     //  1,507,328 (23 x 64K)
  unsigned*       hflags  = (unsigned*)(ws + 16924672);           //     50,176 (98 x 512)
  unsigned*       fflags  = (unsigned*)(ws + 16974848);           //     35,328 (69 x 512)
  const size_t need = 17010176;
  if (ws_size < need) return;

  // Zero: initial hidden buffers (index 0 of each pool) + both flag areas.
  hipMemsetAsync((void*)h0pool, 0, 65536, stream);
  hipMemsetAsync((void*)h1pool, 0, 65536, stream);
  hipMemsetAsync((void*)hflags, 0, 50176 + 35328, stream);

  float* out_r = (float*)d_out;                          // [B][T][R]
  float* out_s = out_r + (size_t)kB*kT*kR;               // [B][T][S]

  hipLaunchKernelGGL(convert_weights, dim3(256), dim3(512), 0, stream,
                     W_sout, WsT2_bf, W_state, WstT_bf, W_reward, Wr_bf);
  hipLaunchKernelGGL(encode_fa_kernel, dim3(kT*kB), dim3(256), 0, stream,
                     future_a, W_action, b_action, g_an, b_an, fa_bf);
  hipLaunchKernelGGL(encode_seq0_kernel, dim3(kSEQ*kB), dim3(256), 0, stream,
                     history_s, history_a, present_s,
                     W_state, b_state, g_sn, b_sn,
                     W_action, b_action, g_an, b_an, fa_bf, seq0_bf);
  hipLaunchKernelGGL(gru_hist, dim3(G), dim3(BT), 0, stream,
                     gru_Wi, gru_Wh, gru_bi, gru_bh,
                     seq0_bf, h0pool, h1pool, hflags);
  hipLaunchKernelGGL(gru_fut, dim3(G), dim3(BT), 0, stream,
                     gru_Wi, gru_Wh, gru_bi, gru_bh,
                     WsT2_bf, b_sout, Wr_bf, b_reward, WstT_bf, b_state,
                     g_sn, b_sn, fa_bf,
                     h0pool, h1pool, xbpool, fflags,
                     out_r, out_s);
}

// Round 6
// 1471.616 us; speedup vs baseline: 1.0752x; 1.0752x over previous
//
#include <hip/hip_runtime.h>
#include <cmath>

// Problem dims (fixed by the reference)
constexpr int kB = 32, kH = 48, kT = 24, kS = 256, kA = 64, kR = 8, kF = 1024;
constexpr int kSEQ = kH + 1;           // 49 = history + present step
constexpr float kEPS = 1e-5f;

// Persistent-kernel config: 128 blocks x 512 thr (8 waves).
// Blocks 0..63: layer-0 f-tiles (16 cols). Blocks 64..127: layer-1.
// Blocks 0..31 also run the fused head stage (one batch each).
constexpr int G  = 128;
constexpr int BT = 512;

typedef __attribute__((ext_vector_type(8))) short short8;   // 8 x bf16
typedef __attribute__((ext_vector_type(4))) float f32x4;

union U4S8 { uint4 u; short8 s; };

__device__ __forceinline__ unsigned bfbits(float x) {  // RNE f32->bf16
  unsigned u = __float_as_uint(x);
  return (u + 0x7fffu + ((u >> 16) & 1u)) >> 16;
}
__device__ __forceinline__ float bf_lo(unsigned u) { return __uint_as_float(u << 16); }
__device__ __forceinline__ float bf_hi(unsigned u) { return __uint_as_float(u & 0xffff0000u); }
__device__ __forceinline__ float bf2f(unsigned short h) {
  return __uint_as_float(((unsigned)h) << 16);
}
__device__ __forceinline__ float gelu_f(float x) {
  return 0.5f * x * (1.0f + erff(x * 0.7071067811865476f));
}
__device__ __forceinline__ float sigmoid_f(float x) {
  return 1.0f / (1.0f + expf(-x));
}

// sc1 (LLC write-through) store: makes produced data visible to all XCDs.
__device__ __forceinline__ void coh_st(unsigned* p, unsigned v) {
  __hip_atomic_store(p, v, __ATOMIC_RELAXED, __HIP_MEMORY_SCOPE_AGENT);
}

// ---------------- R14 sync primitives --------------------------------------
// wwait: per-WAVE wait. All 64 lanes poll the same dword (coalesces to one
// broadcast transaction per iteration); s_sleep(1) backoff caps line pressure
// (R13 lesson: pollers/line is the sensitive variable).
__device__ __forceinline__ void wwait(const unsigned* line, unsigned tgt) {
  for (;;) {
    unsigned v;
    asm volatile("global_load_dword %0, %1, off sc0 sc1\n\t"
                 "s_waitcnt vmcnt(0)"
                 : "=v"(v) : "v"(line) : "memory");
    if (v >= tgt) break;
    __builtin_amdgcn_s_sleep(1);
  }
}
// wait4: block-level wait on up to 4 lines (thread0 polls), ends in barrier.
__device__ __forceinline__ void wait4(const unsigned* fl,
                                      unsigned t0, unsigned t1,
                                      unsigned t2, unsigned t3) {
  if (threadIdx.x == 0) {
    for (;;) {
      unsigned a, b, c, d;
      asm volatile(
        "global_load_dword %0, %4, off sc0 sc1\n\t"
        "global_load_dword %1, %5, off sc0 sc1\n\t"
        "global_load_dword %2, %6, off sc0 sc1\n\t"
        "global_load_dword %3, %7, off sc0 sc1\n\t"
        "s_waitcnt vmcnt(0)"
        : "=&v"(a), "=&v"(b), "=&v"(c), "=&v"(d)
        : "v"(fl), "v"(fl + 32), "v"(fl + 64), "v"(fl + 96)
        : "memory");
      if (a >= t0 && b >= t1 && c >= t2 && d >= t3) break;
      __builtin_amdgcn_s_sleep(1);
    }
  }
  __syncthreads();
}
// sig_oct: producer block fb bumps its octet's line (8 adders/line).
// Caller must be past a __syncthreads() that followed the data stores.
__device__ __forceinline__ void sig_oct(unsigned* fl, int fb) {
  if (threadIdx.x == 0)
    __hip_atomic_fetch_add(fl + ((fb >> 3) & 7) * 32, 1u,
                           __ATOMIC_RELAXED, __HIP_MEMORY_SCOPE_AGENT);
}
// sig16: F3 producer b bumps line (b>>4): 16 adders/line, 2 lines.
__device__ __forceinline__ void sig16(unsigned* fl, int b) {
  if (threadIdx.x == 0)
    __hip_atomic_fetch_add(fl + ((b >> 4) & 1) * 32, 1u,
                           __ATOMIC_RELAXED, __HIP_MEMORY_SCOPE_AGENT);
}

// ---------------- one GRU layer step via MFMA ------------------------------
// Block owns 16 f-cols of one layer. Wave wv = k-slice [wv*128, wv*128+128).
// Wave wv's inputs come ONLY from producer blocks [8wv, 8wv+8) -> per-wave
// octet waits. Cold operand's frags are loaded BEFORE the hot wait so their
// LLC fetch hides under it. x/h are PLAIN CACHED loads (fresh rotation
// addresses -> L2 must miss and fill from LLC where sc1 stores landed).
__device__ __forceinline__ void layer_stage(
    const unsigned short* __restrict__ xsrc,   // [32][1024] bf16
    const unsigned short* __restrict__ hsrc,   // [32][1024] bf16
    unsigned short* __restrict__ hdst,         // [32][1024] bf16 (sc1 stores)
    const unsigned* xw8,     // per-wave octet wait before x loads (or null)
    const unsigned* hw8,     // per-wave octet wait before h loads (or null)
    const unsigned* xblk2,   // block-level 2-line wait (16,16) before x (or null)
    int hfirst,              // 1: h loads first (h cold); 0: x first (x cold)
    const short8 (&Bf)[2][3][4],
    float bR, float bZ, float bIN, float bHN,
    float& h_old, float* part, int fb)
{
  const int tid = threadIdx.x;
  const int wv = tid >> 6, l = tid & 63, q = l >> 4, c = l & 15;

  short8 Ax[2][4], Ah[2][4];
  const int base = c*1024 + wv*128 + q*8;

  if (hfirst) {
    if (hw8) wwait(hw8 + wv*32, 8u);
    #pragma unroll
    for (int mt = 0; mt < 2; mt++)
      #pragma unroll
      for (int j = 0; j < 4; j++)
        Ah[mt][j] = *(const short8*)(hsrc + base + mt*16*1024 + j*32);
    if (xblk2) wait4(xblk2, 16u, 16u, 0u, 0u);
    if (xw8) wwait(xw8 + wv*32, 8u);
    #pragma unroll
    for (int mt = 0; mt < 2; mt++)
      #pragma unroll
      for (int j = 0; j < 4; j++)
        Ax[mt][j] = *(const short8*)(xsrc + base + mt*16*1024 + j*32);
  } else {
    #pragma unroll
    for (int mt = 0; mt < 2; mt++)
      #pragma unroll
      for (int j = 0; j < 4; j++)
        Ax[mt][j] = *(const short8*)(xsrc + base + mt*16*1024 + j*32);
    if (hw8) wwait(hw8 + wv*32, 8u);
    #pragma unroll
    for (int mt = 0; mt < 2; mt++)
      #pragma unroll
      for (int j = 0; j < 4; j++)
        Ah[mt][j] = *(const short8*)(hsrc + base + mt*16*1024 + j*32);
  }

  f32x4 C[4][2];
  #pragma unroll
  for (int s = 0; s < 4; s++)
    #pragma unroll
    for (int mt = 0; mt < 2; mt++)
      C[s][mt] = (f32x4){0.f, 0.f, 0.f, 0.f};

  #pragma unroll
  for (int mt = 0; mt < 2; mt++)
    #pragma unroll
    for (int j = 0; j < 4; j++) {
      C[0][mt] = __builtin_amdgcn_mfma_f32_16x16x32_bf16(Ax[mt][j], Bf[0][0][j], C[0][mt], 0, 0, 0);
      C[0][mt] = __builtin_amdgcn_mfma_f32_16x16x32_bf16(Ah[mt][j], Bf[1][0][j], C[0][mt], 0, 0, 0);
      C[1][mt] = __builtin_amdgcn_mfma_f32_16x16x32_bf16(Ax[mt][j], Bf[0][1][j], C[1][mt], 0, 0, 0);
      C[1][mt] = __builtin_amdgcn_mfma_f32_16x16x32_bf16(Ah[mt][j], Bf[1][1][j], C[1][mt], 0, 0, 0);
      C[2][mt] = __builtin_amdgcn_mfma_f32_16x16x32_bf16(Ax[mt][j], Bf[0][2][j], C[2][mt], 0, 0, 0);
      C[3][mt] = __builtin_amdgcn_mfma_f32_16x16x32_bf16(Ah[mt][j], Bf[1][2][j], C[3][mt], 0, 0, 0);
    }

  // k-slice partials -> LDS (swizzled: 2-way/bank over 64 lanes = free).
  const int perm = (wv + l + (l >> 3)) & 7;
  #pragma unroll
  for (int s = 0; s < 4; s++)
    #pragma unroll
    for (int mt = 0; mt < 2; mt++)
      #pragma unroll
      for (int r = 0; r < 4; r++)
        part[((s*2 + mt)*4 + r)*512 + l*8 + perm] = C[s][mt][r];
  __syncthreads();

  // combine: wave wv -> (mtile = wv&1, reg = wv>>1); lane -> one (b,f)
  const int mt_c = wv & 1, rg = wv >> 1;
  const int b_own = mt_c*16 + q*4 + rg;
  float S[4];
  #pragma unroll
  for (int s = 0; s < 4; s++) {
    const float* pp = part + ((s*2 + mt_c)*4 + rg)*512 + l*8;
    f32x4 a = *(const f32x4*)pp;
    f32x4 b = *(const f32x4*)(pp + 4);
    S[s] = ((a[0]+a[1]) + (a[2]+a[3])) + ((b[0]+b[1]) + (b[2]+b[3]));
  }
  float rr = sigmoid_f(S[0] + bR);
  float zz = sigmoid_f(S[1] + bZ);
  float nn = tanhf(S[2] + bIN + rr * (S[3] + bHN));
  float hn = (1.f - zz)*nn + zz*h_old;
  h_old = hn;
  float nb = __shfl_xor(hn, 1);
  if (!(c & 1)) {
    unsigned pk = bfbits(hn) | (bfbits(nb) << 16);
    coh_st((unsigned*)(hdst + b_own*1024 + fb*16 + c), pk);
  }
  __syncthreads();   // drains all waves' stores -> safe to sig after
}

// ---------------- fused head + LN + pres + gelu (blocks 0..31, b=blk) ------
// Weight loads coalesced via transposed layouts (R12).
__device__ __forceinline__ void f3_stage(
    const unsigned short* __restrict__ y_bf, int t,
    const unsigned short* __restrict__ WsT2_bf, const float* __restrict__ b_sout,
    const unsigned short* __restrict__ Wr_bf, const float* __restrict__ b_reward,
    const unsigned short* __restrict__ WstT_bf, const float* __restrict__ b_state,
    const float* __restrict__ g_sn, const float* __restrict__ b_sn,
    const unsigned short* __restrict__ fa_bf,
    float* __restrict__ out_r, float* __restrict__ out_s,
    unsigned short* __restrict__ xbuf_bf, float* part, int b)
{
  const int tid = threadIdx.x;
  float* yb    = part;          // 1024: y in f32
  float* spart = part + 1024;   // 512
  float* s_sh  = part + 1536;   // 256
  float* rpart = part + 1792;   // 64
  float* red1  = part + 2048;   // 512
  float* red2  = part + 2560;   // 512

  {
    unsigned uu = *((const unsigned*)y_bf + b*512 + tid);   // cached (fresh buf)
    yb[tid*2]     = bf_lo(uu);
    yb[tid*2 + 1] = bf_hi(uu);
  }
  __syncthreads();
  {  // s partials: j = tid&255, k-half = tid>>8; coalesced dword loads
    const int j = tid & 255, ksh = tid >> 8;
    const unsigned* wp = (const unsigned*)WsT2_bf + (size_t)ksh*256*256 + j;
    const float* yp = yb + ksh*512;
    float acc = 0.f;
    #pragma unroll 8
    for (int kp = 0; kp < 256; kp++) {
      unsigned w = wp[kp*256];
      acc += bf_lo(w)*yp[2*kp] + bf_hi(w)*yp[2*kp + 1];
    }
    spart[tid] = acc;
  }
  __syncthreads();
  if (tid < 256) {
    float s = spart[tid] + spart[tid + 256] + b_sout[tid];
    out_s[((size_t)b*kT + t)*kS + tid] = s;
    s_sh[tid] = s;
  } else if (tid < 320) {
    const int idx = tid - 256, j = idx >> 3, ks = idx & 7;
    const unsigned short* wr = Wr_bf + j*1024 + ks*128;
    const float* yp = yb + ks*128;
    float acc = 0.f;
    #pragma unroll 4
    for (int k = 0; k < 128; k += 2) {
      unsigned w = *(const unsigned*)(wr + k);
      acc += bf_lo(w)*yp[k] + bf_hi(w)*yp[k+1];
    }
    rpart[idx] = acc;
  }
  __syncthreads();
  if (tid < 8) {
    float a = b_reward[tid];
    #pragma unroll
    for (int ks = 0; ks < 8; ks++) a += rpart[tid*8 + ks];
    out_r[((size_t)b*kT + t)*kR + tid] = tanhf(a);
  }
  if (t == kT - 1) return;   // uniform branch: last step needs no next-x
  __syncthreads();
  // u[f] = b_state[f] + W_state[f,:] @ s ; LN over 1024; x = gelu(LN + fa[t+1])
  const int f0 = tid*2;
  float a0 = b_state[f0], a1 = b_state[f0 + 1];
  {
    const unsigned* wp = (const unsigned*)WstT_bf + (f0 >> 1);
    #pragma unroll 8
    for (int k = 0; k < 256; k++) {
      unsigned w = wp[k*512];
      a0 += bf_lo(w)*s_sh[k];
      a1 += bf_hi(w)*s_sh[k];
    }
  }
  float s1 = a0 + a1, s2 = a0*a0 + a1*a1;
  red1[tid] = s1; red2[tid] = s2;
  __syncthreads();
  for (int off = 256; off > 0; off >>= 1) {
    if (tid < off) { red1[tid] += red1[tid + off]; red2[tid] += red2[tid + off]; }
    __syncthreads();
  }
  const float mean = red1[0] * (1.0f/kF);
  const float var  = red2[0] * (1.0f/kF) - mean*mean;
  const float inv  = rsqrtf(var + kEPS);
  unsigned fu = *((const unsigned*)(fa_bf + ((size_t)(t+1)*kB + b)*kF) + tid);
  float x0 = (a0 - mean)*inv*g_sn[f0]   + b_sn[f0]   + bf_lo(fu);
  float x1 = (a1 - mean)*inv*g_sn[f0+1] + b_sn[f0+1] + bf_hi(fu);
  unsigned pk = bfbits(gelu_f(x0)) | (bfbits(gelu_f(x1)) << 16);
  coh_st((unsigned*)xbuf_bf + b*512 + tid, pk);
}

// ---------------- B-fragment preamble (shared by both kernels) -------------
__device__ __forceinline__ void load_bfrags(
    const float* __restrict__ gru_Wi, const float* __restrict__ gru_Wh,
    int lay, int fb, int wv, int q, int c, short8 (&Bf)[2][3][4])
{
  const size_t WLL = (size_t)3 * kF * kF;
  const float* Wm[2] = { gru_Wi + lay*WLL, gru_Wh + lay*WLL };
  #pragma unroll
  for (int m = 0; m < 2; m++)
    #pragma unroll
    for (int g = 0; g < 3; g++)
      #pragma unroll
      for (int j = 0; j < 4; j++) {
        const float* p = Wm[m] + ((size_t)(g*kF + fb*16 + c))*kF + wv*128 + j*32 + q*8;
        float4 a = *(const float4*)p;
        float4 b = *(const float4*)(p + 4);
        U4S8 u;
        u.u.x = bfbits(a.x) | (bfbits(a.y) << 16);
        u.u.y = bfbits(a.z) | (bfbits(a.w) << 16);
        u.u.z = bfbits(b.x) | (bfbits(b.y) << 16);
        u.u.w = bfbits(b.z) | (bfbits(b.w) << 16);
        Bf[m][g][j] = u.s;
      }
}

// ---------------- persistent kernel 1: history wavefront -------------------
// FH0(s): h0p(s) ready, 8 octet lines, target 8 each. FH1(s) likewise.
__global__ __launch_bounds__(BT, 2) void gru_hist(
    const float* __restrict__ gru_Wi, const float* __restrict__ gru_Wh,
    const float* __restrict__ gru_bi, const float* __restrict__ gru_bh,
    const unsigned short* __restrict__ seq0_bf,
    unsigned short* h0pool, unsigned short* h1pool,
    unsigned* hflags)
{
  __shared__ float part[32 * 512];   // 64 KB
  const int tid = threadIdx.x;
  const int blk = blockIdx.x;
  const int wv = tid >> 6, l = tid & 63, q = l >> 4, c = l & 15;
  const bool isL1 = (blk >= 64);
  const int fb = blk & 63;
  const int lay = isL1 ? 1 : 0;
  const size_t BF = (size_t)kB * kF;

  short8 Bf[2][3][4];
  load_bfrags(gru_Wi, gru_Wh, lay, fb, wv, q, c, Bf);
  const int f = fb*16 + c;
  const float* bi = gru_bi + lay*3*kF;
  const float* bh = gru_bh + lay*3*kF;
  const float bR  = bi[f] + bh[f];
  const float bZ  = bi[kF + f] + bh[kF + f];
  const float bIN = bi[2*kF + f];
  const float bHN = bh[2*kF + f];

  float h_old = 0.f;

  #define H0P(i) (h0pool + (size_t)(i)*BF)
  #define H1P(i) (h1pool + (size_t)(i)*BF)
  #define FH0(s) (hflags + (size_t)((s) - 1) * 256)
  #define FH1(s) (hflags + (size_t)(48 + (s)) * 256)

  // L0 at s (s<49): x=seq0[s] (cold), h=h0p(s) (hot) -> h0p(s+1)
  // L1 at s (s>=1): x=h0p(s) (hot),  h=h1p(s-1)      -> h1p(s)
  for (int s = 0; s < 50; s++) {
    if (!isL1) {
      if (s < 49) {
        layer_stage(seq0_bf + (size_t)s*BF, H0P(s), H0P(s+1),
                    nullptr, (s >= 1) ? FH0(s) : nullptr, nullptr, /*hfirst=*/0,
                    Bf, bR, bZ, bIN, bHN, h_old, part, fb);
        sig_oct(FH0(s+1), fb);
      }
    } else {
      if (s >= 1) {
        layer_stage(H0P(s), H1P(s-1), H1P(s),
                    FH0(s), (s >= 2) ? FH1(s-1) : nullptr, nullptr, /*hfirst=*/1,
                    Bf, bR, bZ, bIN, bHN, h_old, part, fb);
        sig_oct(FH1(s), fb);
      }
    }
  }
  #undef H0P
  #undef H1P
  #undef FH0
  #undef FH1
}

// ---------------- persistent kernel 2: future chain ------------------------
// FH0F(t): h0p(50+t) ready (8 octet lines). FH1F(t): h1p(50+t). FXF(t):
// xbp(t) ready (2 lines x 16 adders).
__global__ __launch_bounds__(BT, 2) void gru_fut(
    const float* __restrict__ gru_Wi, const float* __restrict__ gru_Wh,
    const float* __restrict__ gru_bi, const float* __restrict__ gru_bh,
    const unsigned short* __restrict__ WsT2_bf, const float* __restrict__ b_sout,
    const unsigned short* __restrict__ Wr_bf, const float* __restrict__ b_reward,
    const unsigned short* __restrict__ WstT_bf, const float* __restrict__ b_state,
    const float* __restrict__ g_sn, const float* __restrict__ b_sn,
    const unsigned short* __restrict__ fa_bf,
    unsigned short* h0pool, unsigned short* h1pool, unsigned short* xbpool,
    unsigned* fflags,
    float* __restrict__ out_r, float* __restrict__ out_s)
{
  __shared__ float part[32 * 512];   // 64 KB
  const int tid = threadIdx.x;
  const int blk = blockIdx.x;
  const int wv = tid >> 6, l = tid & 63, q = l >> 4, c = l & 15;
  const bool isL1 = (blk >= 64);
  const int fb = blk & 63;
  const int lay = isL1 ? 1 : 0;
  const size_t BF = (size_t)kB * kF;

  short8 Bf[2][3][4];
  load_bfrags(gru_Wi, gru_Wh, lay, fb, wv, q, c, Bf);
  const int f = fb*16 + c;
  const float* bi = gru_bi + lay*3*kF;
  const float* bh = gru_bh + lay*3*kF;
  const float bR  = bi[f] + bh[f];
  const float bZ  = bi[kF + f] + bh[kF + f];
  const float bIN = bi[2*kF + f];
  const float bHN = bh[2*kF + f];

  #define H0P(i) (h0pool + (size_t)(i)*BF)
  #define H1P(i) (h1pool + (size_t)(i)*BF)
  #define XBP(i) (xbpool + (size_t)(i)*BF)
  #define FH0F(t) (fflags + (size_t)(t) * 256)
  #define FH1F(t) (fflags + (size_t)(23 + (t)) * 256)
  #define FXF(t)  (fflags + (size_t)46 * 256 + (size_t)(t) * 64)

  // h_old reload from pools (one bf16 rounding at the kernel boundary).
  const int b_own = (wv & 1)*16 + q*4 + (wv >> 1);
  float h_old;
  {
    const unsigned short* hs = isL1 ? H1P(49) : H0P(49);
    h_old = bf2f(hs[b_own*1024 + f]);
  }

  // per t: F3 -> L0 -> L1 (serial feedback chain)
  // F3 at t: y=h1p(49+t), writes xbp(t) (t<23)
  // L0 at t: x=xbp(t) (hot), h=h0p(49+t) (cold) -> h0p(50+t)
  // L1 at t: x=h0p(50+t) (hot), h=h1p(49+t) (cold) -> h1p(50+t)
  for (int t = 0; t < kT; t++) {
    if (blk < kB) {
      if (t >= 1) {   // all 8 octet lines of h1p(49+t) = FH1F(t-1)
        wait4(FH1F(t-1), 8u, 8u, 8u, 8u);
        wait4(FH1F(t-1) + 128, 8u, 8u, 8u, 8u);
      }
      f3_stage(H1P(49+t), t, WsT2_bf, b_sout, Wr_bf, b_reward,
               WstT_bf, b_state, g_sn, b_sn, fa_bf,
               out_r, out_s, XBP(t), part, blk);
      if (t < kT - 1) { __syncthreads(); sig16(FXF(t), blk); }
    }
    if (t == kT - 1) break;
    if (!isL1) {
      layer_stage(XBP(t), H0P(49+t), H0P(50+t),
                  nullptr, (t >= 1) ? FH0F(t-1) : nullptr, FXF(t), /*hfirst=*/1,
                  Bf, bR, bZ, bIN, bHN, h_old, part, fb);
      sig_oct(FH0F(t), fb);
    } else {
      layer_stage(H0P(50+t), H1P(49+t), H1P(50+t),
                  FH0F(t), (t >= 1) ? FH1F(t-1) : nullptr, nullptr, /*hfirst=*/1,
                  Bf, bR, bZ, bIN, bHN, h_old, part, fb);
      sig_oct(FH1F(t), fb);
    }
  }
  #undef H0P
  #undef H1P
  #undef XBP
  #undef FH0F
  #undef FH1F
  #undef FXF
}

// ---------------- setup: convert + transpose head weights to bf16 ----------
__global__ __launch_bounds__(512) void convert_weights(
    const float* __restrict__ ws,  unsigned short* __restrict__ wsT2,
    const float* __restrict__ wst, unsigned short* __restrict__ wstT,
    const float* __restrict__ wr,  unsigned short* __restrict__ o3)
{
  const int stride = gridDim.x * blockDim.x;
  const int i0 = blockIdx.x * blockDim.x + threadIdx.x;
  // WsT2[(k>>1)*512 + j*2 + (k&1)] = bf16(W_sout[j][k]); j=i>>10, k=i&1023
  for (int i = i0; i < kS*kF; i += stride) {
    const int j = i >> 10, k = i & 1023;
    wsT2[(k >> 1)*512 + j*2 + (k & 1)] = (unsigned short)bfbits(ws[i]);
  }
  // WstT[k*1024 + f] = bf16(W_state[f][k]); f=i>>8, k=i&255
  for (int i = i0; i < kF*kS; i += stride) {
    const int ff = i >> 8, k = i & 255;
    wstT[k*1024 + ff] = (unsigned short)bfbits(wst[i]);
  }
  for (int i = i0; i < kR*kF; i += stride) o3[i] = (unsigned short)bfbits(wr[i]);
}

// ---------------- encoder: fa_bf[t][b][f] = bf16(LN(future_a@Wa^T+ba)*g+b) -
__global__ __launch_bounds__(256) void encode_fa_kernel(
    const float* __restrict__ future_a,
    const float* __restrict__ W_action, const float* __restrict__ b_action,
    const float* __restrict__ g_an, const float* __restrict__ b_an,
    unsigned short* __restrict__ fa_bf)
{
  __shared__ __align__(16) float arow[kA];
  __shared__ float red1[256], red2[256];
  const int bid = blockIdx.x;
  const int b = bid & (kB - 1);
  const int t = bid >> 5;
  const int tid = threadIdx.x;
  if (tid < kA) arow[tid] = future_a[((size_t)b*kT + t)*kA + tid];
  __syncthreads();
  float v[4]; float s1 = 0.f, s2 = 0.f;
  #pragma unroll
  for (int j = 0; j < 4; j++) {
    const int ff = tid + j*256;
    const float* wr = W_action + (size_t)ff*kA;
    float acc = b_action[ff];
    for (int k = 0; k < kA; k += 4) {
      float4 w  = *(const float4*)(wr + k);
      float4 xv = *(const float4*)(arow + k);
      acc += xv.x*w.x + xv.y*w.y + xv.z*w.z + xv.w*w.w;
    }
    v[j] = acc; s1 += acc; s2 += acc*acc;
  }
  red1[tid] = s1; red2[tid] = s2;
  __syncthreads();
  for (int off = 128; off > 0; off >>= 1) {
    if (tid < off) { red1[tid] += red1[tid+off]; red2[tid] += red2[tid+off]; }
    __syncthreads();
  }
  const float m = red1[0] * (1.0f/kF);
  const float va = red2[0] * (1.0f/kF) - m*m;
  const float inv = rsqrtf(va + kEPS);
  #pragma unroll
  for (int j = 0; j < 4; j++) {
    const int ff = tid + j*256;
    fa_bf[((size_t)t*kB + b)*kF + ff] =
        (unsigned short)bfbits((v[j] - m)*inv*g_an[ff] + b_an[ff]);
  }
}

// ---------------- encoder: seq0_bf = bf16(gelu(LN_s + LN_a)) ---------------
__global__ __launch_bounds__(256) void encode_seq0_kernel(
    const float* __restrict__ history_s, const float* __restrict__ history_a,
    const float* __restrict__ present_s,
    const float* __restrict__ W_state, const float* __restrict__ b_state,
    const float* __restrict__ g_sn, const float* __restrict__ b_sn,
    const float* __restrict__ W_action, const float* __restrict__ b_action,
    const float* __restrict__ g_an, const float* __restrict__ b_an,
    const unsigned short* __restrict__ fa_bf, unsigned short* __restrict__ seq0_bf)
{
  __shared__ __align__(16) float srow[kS];
  __shared__ __align__(16) float arow[kA];
  __shared__ float red1[256], red2[256];
  const int bid = blockIdx.x;
  const int b = bid & (kB - 1);
  const int t = bid >> 5;                 // 0..48
  const int tid = threadIdx.x;
  const bool hist = (t < kH);
  const float* sp = hist ? (history_s + ((size_t)b*kH + t)*kS)
                         : (present_s + (size_t)b*kS);
  srow[tid] = sp[tid];
  if (hist && tid < kA) arow[tid] = history_a[((size_t)b*kH + t)*kA + tid];
  __syncthreads();

  float u[4]; float s1 = 0.f, s2 = 0.f;
  #pragma unroll
  for (int j = 0; j < 4; j++) {
    const int ff = tid + j*256;
    const float* wr = W_state + (size_t)ff*kS;
    float acc = b_state[ff];
    for (int k = 0; k < kS; k += 4) {
      float4 w  = *(const float4*)(wr + k);
      float4 xv = *(const float4*)(srow + k);
      acc += xv.x*w.x + xv.y*w.y + xv.z*w.z + xv.w*w.w;
    }
    u[j] = acc; s1 += acc; s2 += acc*acc;
  }
  red1[tid] = s1; red2[tid] = s2;
  __syncthreads();
  for (int off = 128; off > 0; off >>= 1) {
    if (tid < off) { red1[tid] += red1[tid+off]; red2[tid] += red2[tid+off]; }
    __syncthreads();
  }
  const float mu = red1[0] * (1.0f/kF);
  const float vu = red2[0] * (1.0f/kF) - mu*mu;
  const float iu = rsqrtf(vu + kEPS);
  __syncthreads();

  if (hist) {
    float v[4]; s1 = 0.f; s2 = 0.f;
    #pragma unroll
    for (int j = 0; j < 4; j++) {
      const int ff = tid + j*256;
      const float* wr = W_action + (size_t)ff*kA;
      float acc = b_action[ff];
      for (int k = 0; k < kA; k += 4) {
        float4 w  = *(const float4*)(wr + k);
        float4 xv = *(const float4*)(arow + k);
        acc += xv.x*w.x + xv.y*w.y + xv.z*w.z + xv.w*w.w;
      }
      v[j] = acc; s1 += acc; s2 += acc*acc;
    }
    red1[tid] = s1; red2[tid] = s2;
    __syncthreads();
    for (int off = 128; off > 0; off >>= 1) {
      if (tid < off) { red1[tid] += red1[tid+off]; red2[tid] += red2[tid+off]; }
      __syncthreads();
    }
    const float mv = red1[0] * (1.0f/kF);
    const float vv = red2[0] * (1.0f/kF) - mv*mv;
    const float iv = rsqrtf(vv + kEPS);
    #pragma unroll
    for (int j = 0; j < 4; j++) {
      const int ff = tid + j*256;
      const float un = (u[j] - mu)*iu*g_sn[ff] + b_sn[ff];
      const float vn = (v[j] - mv)*iv*g_an[ff] + b_an[ff];
      seq0_bf[((size_t)t*kB + b)*kF + ff] = (unsigned short)bfbits(gelu_f(un + vn));
    }
  } else {
    #pragma unroll
    for (int j = 0; j < 4; j++) {
      const int ff = tid + j*256;
      const float un = (u[j] - mu)*iu*g_sn[ff] + b_sn[ff];
      seq0_bf[((size_t)t*kB + b)*kF + ff] =
          (unsigned short)bfbits(gelu_f(un + bf2f(fa_bf[(size_t)b*kF + ff])));
    }
  }
}

// ---------------- host launcher -------------------------------------------
extern "C" void kernel_launch(void* const* d_in, const int* in_sizes, int n_in,
                              void* d_out, int out_size, void* d_ws, size_t ws_size,
                              hipStream_t stream) {
  (void)in_sizes; (void)n_in; (void)out_size;
  const float* history_s = (const float*)d_in[0];
  const float* history_a = (const float*)d_in[1];
  const float* present_s = (const float*)d_in[2];
  /* d_in[3] future_s: unused by the reference forward */
  const float* future_a  = (const float*)d_in[4];
  const float* W_state   = (const float*)d_in[5];
  const float* b_state   = (const float*)d_in[6];
  const float* g_sn      = (const float*)d_in[7];
  const float* b_sn      = (const float*)d_in[8];
  const float* W_action  = (const float*)d_in[9];
  const float* b_action  = (const float*)d_in[10];
  const float* g_an      = (const float*)d_in[11];
  const float* b_an      = (const float*)d_in[12];
  const float* gru_Wi    = (const float*)d_in[13];
  const float* gru_Wh    = (const float*)d_in[14];
  const float* gru_bi    = (const float*)d_in[15];
  const float* gru_bh    = (const float*)d_in[16];
  const float* W_reward  = (const float*)d_in[17];
  const float* b_reward  = (const float*)d_in[18];
  const float* W_sout    = (const float*)d_in[19];
  const float* b_sout    = (const float*)d_in[20];

  // workspace layout (bytes, 16-aligned). Rotation pools: 73+73 h buffers
  // (64 KB each) + 23 xbuf. Flags: hist 98 stages x 8 lines (100,352 B);
  // fut 46 x 8 lines + 23 x 2 lines (52,992 B).
  char* ws = (char*)d_ws;
  unsigned short* seq0_bf = (unsigned short*)(ws + 0);            //  3,211,264
  unsigned short* fa_bf   = (unsigned short*)(ws + 3211264);      //  1,572,864
  unsigned short* WsT2_bf = (unsigned short*)(ws + 4784128);      //    524,288
  unsigned short* WstT_bf = (unsigned short*)(ws + 5308416);      //    524,288
  unsigned short* Wr_bf   = (unsigned short*)(ws + 5832704);      //     16,384
  unsigned short* h0pool  = (unsigned short*)(ws + 5849088);      //  4,784,128 (73 x 64K)
  unsigned short* h1pool  = (unsigned short*)(ws + 10633216);     //  4,784,128 (73 x 64K)
  unsigned short* xbpool  = (unsigned short*)(ws + 15417344);     //  1,507,328 (23 x 64K)
  unsigned*       hflags  = (unsigned*)(ws + 16924672);           //    100,352
  unsigned*       fflags  = (unsigned*)(ws + 17025024);           //     52,992
  const size_t need = 17078016;
  if (ws_size < need) return;

  // Zero: initial hidden buffers (index 0 of each pool) + both flag areas.
  hipMemsetAsync((void*)h0pool, 0, 65536, stream);
  hipMemsetAsync((void*)h1pool, 0, 65536, stream);
  hipMemsetAsync((void*)hflags, 0, 100352 + 52992, stream);

  float* out_r = (float*)d_out;                          // [B][T][R]
  float* out_s = out_r + (size_t)kB*kT*kR;               // [B][T][S]

  hipLaunchKernelGGL(convert_weights, dim3(256), dim3(512), 0, stream,
                     W_sout, WsT2_bf, W_state, WstT_bf, W_reward, Wr_bf);
  hipLaunchKernelGGL(encode_fa_kernel, dim3(kT*kB), dim3(256), 0, stream,
                     future_a, W_action, b_action, g_an, b_an, fa_bf);
  hipLaunchKernelGGL(encode_seq0_kernel, dim3(kSEQ*kB), dim3(256), 0, stream,
                     history_s, history_a, present_s,
                     W_state, b_state, g_sn, b_sn,
                     W_action, b_action, g_an, b_an, fa_bf, seq0_bf);
  hipLaunchKernelGGL(gru_hist, dim3(G), dim3(BT), 0, stream,
                     gru_Wi, gru_Wh, gru_bi, gru_bh,
                     seq0_bf, h0pool, h1pool, hflags);
  hipLaunchKernelGGL(gru_fut, dim3(G), dim3(BT), 0, stream,
                     gru_Wi, gru_Wh, gru_bi, gru_bh,
                     WsT2_bf, b_sout, Wr_bf, b_reward, WstT_bf, b_state,
                     g_sn, b_sn, fa_bf,
                     h0pool, h1pool, xbpool, fflags,
                     out_r, out_s);
}